// Round 1
// baseline (3915.060 us; speedup 1.0000x reference)
//
#include <hip/hip_runtime.h>
#include <cstdint>
#include <cstddef>

// Problem constants
#define SEQL   256
#define NBATCH 64
#define HDIM   512
#define ZDIM   2048   // 4*OUT
#define KDIM   1536   // in_dim

typedef __attribute__((ext_vector_type(8))) short short8;
typedef __attribute__((ext_vector_type(4))) float f32x4;
typedef __attribute__((ext_vector_type(4))) float f4v;

static __device__ __forceinline__ unsigned short f2bf(float f) {
  union { float f; unsigned u; } v; v.f = f;
  unsigned u = v.u;
  unsigned r = (u + 0x7FFFu + ((u >> 16) & 1u)) >> 16;   // RNE
  return (unsigned short)r;
}
static __device__ __forceinline__ float bf2f(unsigned short s) {
  union { unsigned u; float f; } v; v.u = ((unsigned)s) << 16; return v.f;
}
static __device__ __forceinline__ float sigm(float x)  { return 1.f / (1.f + __expf(-x)); }
static __device__ __forceinline__ float tanh_f(float x){ return 1.f - 2.f / (__expf(2.f * x) + 1.f); }

static __device__ __forceinline__ void gl_lds16(const void* g, void* l) {
  // global -> LDS direct copy, 16B per lane. LDS dest is wave-uniform base + lane*16.
  __builtin_amdgcn_global_load_lds((const __attribute__((address_space(1))) unsigned int*)g,
                                   (__attribute__((address_space(3))) unsigned int*)l, 16, 0, 0);
}

// ---------------------------------------------------------------- prep kernels

// x (b,t,k) f32 -> Xb[r][k] bf16 with r = t*64 + b
__global__ __launch_bounds__(256) void k_convx(const float* __restrict__ x,
                                               unsigned short* __restrict__ Xb) {
  int i = blockIdx.x * 256 + threadIdx.x;        // 1,048,576 threads, 8 elems each
  int k8 = (i & 63) * 8;
  int r  = i >> 6;                               // 0..16383
  int b  = r & 63, t = r >> 6;
  const float* src = x + ((size_t)(b * SEQL + t) * HDIM + k8);
  f4v v0 = *(const f4v*)src;
  f4v v1 = *(const f4v*)(src + 4);
  short8 o;
#pragma unroll
  for (int j = 0; j < 4; ++j) o[j] = (short)f2bf(v0[j]);
#pragma unroll
  for (int j = 0; j < 4; ++j) o[4 + j] = (short)f2bf(v1[j]);
  *(short8*)(Xb + (size_t)r * HDIM + k8) = o;
}

// g (64,512) f32 -> bf16
__global__ __launch_bounds__(256) void k_convg(const float* __restrict__ g,
                                               unsigned short* __restrict__ gbf) {
  int i = blockIdx.x * 256 + threadIdx.x;        // 4096 threads * 8
  int k8 = (i & 63) * 8;
  int row = i >> 6;
  const float* src = g + ((size_t)row * HDIM + k8);
  f4v v0 = *(const f4v*)src;
  f4v v1 = *(const f4v*)(src + 4);
  short8 o;
#pragma unroll
  for (int j = 0; j < 4; ++j) o[j] = (short)f2bf(v0[j]);
#pragma unroll
  for (int j = 0; j < 4; ++j) o[4 + j] = (short)f2bf(v1[j]);
  *(short8*)(gbf + (size_t)row * HDIM + k8) = o;
}

// W (1536,2048) f32 -> Wt (2048,1536) bf16 (transposed, so MFMA B-frags are contiguous in k)
__global__ __launch_bounds__(256) void k_trans(const float* __restrict__ W,
                                               unsigned short* __restrict__ Wt) {
  __shared__ float tile[32][33];
  int tx = threadIdx.x & 31, ty = threadIdx.x >> 5;    // 32 x 8
  int n0 = blockIdx.x * 32;                            // over 2048
  int j0 = blockIdx.y * 32;                            // over 1536
#pragma unroll
  for (int jj = 0; jj < 4; ++jj)
    tile[ty + jj * 8][tx] = W[(size_t)(j0 + ty + jj * 8) * ZDIM + n0 + tx];
  __syncthreads();
#pragma unroll
  for (int jj = 0; jj < 4; ++jj)
    Wt[(size_t)(n0 + ty + jj * 8) * KDIM + j0 + tx] = f2bf(tile[tx][ty + jj * 8]);
}

// gbuf[64][2048] = g @ Wg + bias  (bf16 MFMA, frags direct from global; tiny kernel)
__global__ __launch_bounds__(256) void k_gb(const unsigned short* __restrict__ gbf,
                                            const unsigned short* __restrict__ Wt,
                                            const float* __restrict__ bias,
                                            float* __restrict__ gbuf) {
  int tid = threadIdx.x, l = tid & 63, w = tid >> 6;
  int n0 = blockIdx.x * 64 + w * 16;
  f32x4 acc[4] = {};
#pragma unroll
  for (int kb = 0; kb < 16; ++kb) {
    // B: Wg^T[n][k] = Wt[n][1024+k]; byte = n*3072 + 2048 + k*2
    short8 bfr = *(const short8*)((const char*)Wt + (size_t)(n0 + (l & 15)) * 3072
                                  + 2048 + kb * 64 + (l >> 4) * 16);
#pragma unroll
    for (int mi = 0; mi < 4; ++mi) {
      short8 afr = *(const short8*)((const char*)gbf + (size_t)(mi * 16 + (l & 15)) * 1024
                                    + kb * 64 + (l >> 4) * 16);
      acc[mi] = __builtin_amdgcn_mfma_f32_16x16x32_bf16(afr, bfr, acc[mi], 0, 0, 0);
    }
  }
  int r0 = (l >> 4) * 4, cq = l & 15;
#pragma unroll
  for (int mi = 0; mi < 4; ++mi)
#pragma unroll
    for (int reg = 0; reg < 4; ++reg) {
      int row = mi * 16 + r0 + reg, col = n0 + cq;
      gbuf[(size_t)row * ZDIM + col] = acc[mi][reg] + bias[col];
    }
}

// ------------------------------------------------- phase-1 GEMM: zpre = Xb @ Wx^T + gbuf
// M=16384, N=2048, K=512. 128x128 tile, 4 waves, BK=64, global_load_lds(16B) staging.
__global__ __launch_bounds__(256, 2) void k_gemm_p1(const unsigned short* __restrict__ Xb,
                                                    const unsigned short* __restrict__ Wt,
                                                    const float* __restrict__ gbuf,
                                                    unsigned short* __restrict__ zpre) {
  __shared__ unsigned char sm[32768];   // A tile 128x64 bf16 @0, B tile 128x64 bf16 @16384
  int tm = blockIdx.x, tn = blockIdx.y;
  int tid = threadIdx.x, l = tid & 63, w = tid >> 6;
  int m0w = (w & 1) * 64, n0w = (w >> 1) * 64;
  f32x4 acc[4][4] = {};

  for (int k0 = 0; k0 < HDIM; k0 += 64) {
    // stage 32KB as 32 x 1KB chunks; chunk c = j*4 + w
#pragma unroll
    for (int j = 0; j < 8; ++j) {
      int c = j * 4 + w;
      int lane_row = l >> 3;
      int kb = (l & 7) * 16;
      const char* gsrc;
      if (c < 16) {            // A rows c*8 .. c*8+7
        int row = c * 8 + lane_row;
        gsrc = (const char*)Xb + (size_t)(tm * 128 + row) * 1024 + k0 * 2 + kb;
      } else {                 // B rows (n of Wt)
        int row = (c - 16) * 8 + lane_row;
        gsrc = (const char*)Wt + (size_t)(tn * 128 + row) * 3072 + k0 * 2 + kb;
      }
      gl_lds16(gsrc, (char*)sm + c * 1024);
    }
    __syncthreads();   // waits vmcnt(0) for global_load_lds

#pragma unroll
    for (int kk = 0; kk < 64; kk += 32) {
      short8 af[4], bf[4];
#pragma unroll
      for (int mi = 0; mi < 4; ++mi)
        af[mi] = *(const short8*)((const char*)sm + (size_t)(m0w + mi * 16 + (l & 15)) * 128
                                  + (kk + (l >> 4) * 8) * 2);
#pragma unroll
      for (int ni = 0; ni < 4; ++ni)
        bf[ni] = *(const short8*)((const char*)sm + 16384 + (size_t)(n0w + ni * 16 + (l & 15)) * 128
                                  + (kk + (l >> 4) * 8) * 2);
#pragma unroll
      for (int mi = 0; mi < 4; ++mi)
#pragma unroll
        for (int ni = 0; ni < 4; ++ni)
          acc[mi][ni] = __builtin_amdgcn_mfma_f32_16x16x32_bf16(af[mi], bf[ni], acc[mi][ni], 0, 0, 0);
    }
    __syncthreads();
  }

  int r0 = (l >> 4) * 4, cq = l & 15;
#pragma unroll
  for (int mi = 0; mi < 4; ++mi)
#pragma unroll
    for (int ni = 0; ni < 4; ++ni) {
      int col = tn * 128 + n0w + ni * 16 + cq;
#pragma unroll
      for (int reg = 0; reg < 4; ++reg) {
        int row = tm * 128 + m0w + mi * 16 + r0 + reg;   // row = t*64 + b
        float v = acc[mi][ni][reg] + gbuf[(size_t)(row & 63) * ZDIM + col];
        zpre[(size_t)row * ZDIM + col] = f2bf(v);
      }
    }
}

// ---------------------------------------------------------- persistent recurrence
// 256 wgs: dir(2) x colgroup(32, 16 h-cols) x batchgroup(4, 16 rows). 4 waves = 4 gates.
#define NWG 256

static __device__ __forceinline__ void grid_barrier(unsigned* cnt, unsigned target) {
  __syncthreads();
  if (threadIdx.x == 0) {
    __hip_atomic_fetch_add(cnt, 1u, __ATOMIC_RELEASE, __HIP_MEMORY_SCOPE_AGENT);
    long guard = 0;
    while (__hip_atomic_load(cnt, __ATOMIC_ACQUIRE, __HIP_MEMORY_SCOPE_AGENT) < target) {
      __builtin_amdgcn_s_sleep(2);
      if (++guard > (1L << 20)) break;   // hang guard (should never trigger)
    }
  }
  __syncthreads();
}

__global__ __launch_bounds__(256, 1) void k_rec(const unsigned short* __restrict__ Wt,
                                                const unsigned short* __restrict__ zpre,
                                                unsigned short* __restrict__ hbuf, // [2][2][64][512] bf16
                                                unsigned* __restrict__ cnt,
                                                float* __restrict__ out,
                                                float* __restrict__ hstate,
                                                float* __restrict__ cstate) {
  __shared__ short lwh[4 * 16 * 512];   // 64KB: [gate][col][k] bf16, XOR-swizzled rows
  __shared__ float zbuf[4][16][16];

  int tid = threadIdx.x, l = tid & 63, gi = tid >> 6;   // wave = gate (i,f,o,u)
  int wg = blockIdx.x;
  int dir = wg >> 7, rr = wg & 127, cg = rr >> 2, bg = rr & 3;
  int m0 = bg * 16, hc0 = cg * 16;

  // stage Wh slice for this wg's 4x16 z-cols into LDS (resident all 256 steps).
  // content for (col, k) stored at byte col*1024 + (k*2 ^ ((col&7)<<4))
#pragma unroll
  for (int it = 0; it < 16; ++it) {
    int col = it;
    int kbs = l * 16;                        // swizzled byte offset within col row
    int kbyte = kbs ^ ((col & 7) << 4);      // actual k byte
    short8 v = *(const short8*)((const char*)Wt
                + (size_t)(gi * 512 + hc0 + col) * 3072 + 1024 + kbyte);
    *(short8*)((char*)lwh + gi * 16384 + col * 1024 + kbs) = v;
  }

  int r = tid >> 4, q = tid & 15;
  // zero-init h buffer 0 (read at step 0)
  hbuf[((size_t)(0 * 2 + dir) * 64 + m0 + r) * 512 + hc0 + q] = 0;
  __syncthreads();
  unsigned bar = 0;
  grid_barrier(cnt, ++bar * NWG);

  float c_reg = 0.f, h_last = 0.f;

  for (int s = 0; s < SEQL; ++s) {
    int t = dir ? (SEQL - 1 - s) : s;
    int rb = s & 1, wb = rb ^ 1;

    // z-tile GEMM: wave gi computes (16 rows m0..)x(16 cols of gate gi), K=512
    f32x4 acc = {0.f, 0.f, 0.f, 0.f};
    const char* hbase = (const char*)hbuf + (size_t)(rb * 2 + dir) * 64 * 1024;
#pragma unroll
    for (int kb = 0; kb < 16; ++kb) {
      short8 a = *(const short8*)(hbase + (size_t)(m0 + (l & 15)) * 1024
                                  + kb * 64 + (l >> 4) * 16);
      int kbyte = (kb * 64 + (l >> 4) * 16) ^ ((l & 7) << 4);   // (col&7) == (l&15)&7 == l&7
      short8 b = *(const short8*)((const char*)lwh + gi * 16384 + (l & 15) * 1024 + kbyte);
      acc = __builtin_amdgcn_mfma_f32_16x16x32_bf16(a, b, acc, 0, 0, 0);
    }
    {
      int col = l & 15, row0 = (l >> 4) * 4;
#pragma unroll
      for (int reg = 0; reg < 4; ++reg) zbuf[gi][row0 + reg][col] = acc[reg];
    }
    __syncthreads();

    // gate math: thread (r,q) owns (row m0+r, h-col hc0+q); c_reg persistent
    size_t zoff = ((size_t)t * 64 + m0 + r) * ZDIM + hc0 + q;
    float zi = zbuf[0][r][q] + bf2f(zpre[zoff + 0]);
    float zf = zbuf[1][r][q] + bf2f(zpre[zoff + 512]);
    float zo = zbuf[2][r][q] + bf2f(zpre[zoff + 1024]);
    float zu = zbuf[3][r][q] + bf2f(zpre[zoff + 1536]);
    c_reg = sigm(zf) * c_reg + sigm(zi) * tanh_f(zu);
    float h = sigm(zo) * tanh_f(c_reg);
    h_last = h;

    out[((size_t)(m0 + r) * SEQL + t) * 1024 + dir * 512 + hc0 + q] = h;
    hbuf[((size_t)(wb * 2 + dir) * 64 + m0 + r) * 512 + hc0 + q] = f2bf(h);

    grid_barrier(cnt, ++bar * NWG);
  }

  hstate[(size_t)(m0 + r) * 1024 + dir * 512 + hc0 + q] = h_last;
  cstate[(size_t)(m0 + r) * 1024 + dir * 512 + hc0 + q] = c_reg;
}

// ---------------------------------------------------------------------- launch

extern "C" void kernel_launch(void* const* d_in, const int* in_sizes, int n_in,
                              void* d_out, int out_size, void* d_ws, size_t ws_size,
                              hipStream_t stream) {
  const float* x    = (const float*)d_in[0];
  const float* g    = (const float*)d_in[1];
  const float* W    = (const float*)d_in[2];
  const float* bias = (const float*)d_in[3];
  float* out = (float*)d_out;
  float* hstate = out + (size_t)16777216;            // 64*256*1024
  float* cstate = out + (size_t)16842752;            // + 64*1024

  char* ws = (char*)d_ws;
  unsigned*       cnt  = (unsigned*)(ws + 0);
  unsigned short* hbuf = (unsigned short*)(ws + 1024);        // 256KB
  unsigned short* Xb   = (unsigned short*)(ws + 263168);      // 16MB
  unsigned short* Wt   = (unsigned short*)(ws + 17040384);    // 6MB
  unsigned short* gbf  = (unsigned short*)(ws + 23331840);    // 64KB
  float*          gbuf = (float*)(ws + 23397376);             // 512KB
  unsigned short* zpre = (unsigned short*)(ws + 23921664);    // 64MB

  hipMemsetAsync((void*)cnt, 0, 256, stream);

  k_convx<<<4096, 256, 0, stream>>>(x, Xb);
  k_convg<<<16, 256, 0, stream>>>(g, gbf);
  k_trans<<<dim3(64, 48), 256, 0, stream>>>(W, Wt);
  k_gb<<<32, 256, 0, stream>>>(gbf, Wt, bias, gbuf);
  k_gemm_p1<<<dim3(128, 16), 256, 0, stream>>>(Xb, Wt, gbuf, zpre);
  k_rec<<<NWG, 256, 0, stream>>>(Wt, zpre, hbuf, cnt, out, hstate, cstate);
}

// Round 2
// 1817.133 us; speedup vs baseline: 2.1545x; 2.1545x over previous
//
#include <hip/hip_runtime.h>
#include <cstdint>
#include <cstddef>

// Problem constants
#define SEQL   256
#define NBATCH 64
#define HDIM   512
#define ZDIM   2048   // 4*OUT
#define KDIM   1536   // in_dim

typedef __attribute__((ext_vector_type(8))) short short8;
typedef __attribute__((ext_vector_type(4))) float f32x4;
typedef __attribute__((ext_vector_type(4))) float f4v;

static __device__ __forceinline__ unsigned short f2bf(float f) {
  union { float f; unsigned u; } v; v.f = f;
  unsigned u = v.u;
  unsigned r = (u + 0x7FFFu + ((u >> 16) & 1u)) >> 16;   // RNE
  return (unsigned short)r;
}
static __device__ __forceinline__ float bf2f(unsigned short s) {
  union { unsigned u; float f; } v; v.u = ((unsigned)s) << 16; return v.f;
}
static __device__ __forceinline__ float sigm(float x)  { return 1.f / (1.f + __expf(-x)); }
static __device__ __forceinline__ float tanh_f(float x){ return 1.f - 2.f / (__expf(2.f * x) + 1.f); }

static __device__ __forceinline__ void gl_lds16(const void* g, void* l) {
  __builtin_amdgcn_global_load_lds((const __attribute__((address_space(1))) unsigned int*)g,
                                   (__attribute__((address_space(3))) unsigned int*)l, 16, 0, 0);
}

// ---------------------------------------------------------------- prep kernels

// x (b,t,k) f32 -> Xb[r][k] bf16 with r = t*64 + b
__global__ __launch_bounds__(256) void k_convx(const float* __restrict__ x,
                                               unsigned short* __restrict__ Xb) {
  int i = blockIdx.x * 256 + threadIdx.x;
  int k8 = (i & 63) * 8;
  int r  = i >> 6;
  int b  = r & 63, t = r >> 6;
  const float* src = x + ((size_t)(b * SEQL + t) * HDIM + k8);
  f4v v0 = *(const f4v*)src;
  f4v v1 = *(const f4v*)(src + 4);
  short8 o;
#pragma unroll
  for (int j = 0; j < 4; ++j) o[j] = (short)f2bf(v0[j]);
#pragma unroll
  for (int j = 0; j < 4; ++j) o[4 + j] = (short)f2bf(v1[j]);
  *(short8*)(Xb + (size_t)r * HDIM + k8) = o;
}

// g (64,512) f32 -> bf16
__global__ __launch_bounds__(256) void k_convg(const float* __restrict__ g,
                                               unsigned short* __restrict__ gbf) {
  int i = blockIdx.x * 256 + threadIdx.x;
  int k8 = (i & 63) * 8;
  int row = i >> 6;
  const float* src = g + ((size_t)row * HDIM + k8);
  f4v v0 = *(const f4v*)src;
  f4v v1 = *(const f4v*)(src + 4);
  short8 o;
#pragma unroll
  for (int j = 0; j < 4; ++j) o[j] = (short)f2bf(v0[j]);
#pragma unroll
  for (int j = 0; j < 4; ++j) o[4 + j] = (short)f2bf(v1[j]);
  *(short8*)(gbf + (size_t)row * HDIM + k8) = o;
}

// W (1536,2048) f32 -> Wt (2048,1536) bf16 (transposed)
__global__ __launch_bounds__(256) void k_trans(const float* __restrict__ W,
                                               unsigned short* __restrict__ Wt) {
  __shared__ float tile[32][33];
  int tx = threadIdx.x & 31, ty = threadIdx.x >> 5;
  int n0 = blockIdx.x * 32;
  int j0 = blockIdx.y * 32;
#pragma unroll
  for (int jj = 0; jj < 4; ++jj)
    tile[ty + jj * 8][tx] = W[(size_t)(j0 + ty + jj * 8) * ZDIM + n0 + tx];
  __syncthreads();
#pragma unroll
  for (int jj = 0; jj < 4; ++jj)
    Wt[(size_t)(n0 + ty + jj * 8) * KDIM + j0 + tx] = f2bf(tile[tx][ty + jj * 8]);
}

// gbuf[64][2048] = g @ Wg + bias
__global__ __launch_bounds__(256) void k_gb(const unsigned short* __restrict__ gbf,
                                            const unsigned short* __restrict__ Wt,
                                            const float* __restrict__ bias,
                                            float* __restrict__ gbuf) {
  int tid = threadIdx.x, l = tid & 63, w = tid >> 6;
  int n0 = blockIdx.x * 64 + w * 16;
  f32x4 acc[4] = {};
#pragma unroll
  for (int kb = 0; kb < 16; ++kb) {
    short8 bfr = *(const short8*)((const char*)Wt + (size_t)(n0 + (l & 15)) * 3072
                                  + 2048 + kb * 64 + (l >> 4) * 16);
#pragma unroll
    for (int mi = 0; mi < 4; ++mi) {
      short8 afr = *(const short8*)((const char*)gbf + (size_t)(mi * 16 + (l & 15)) * 1024
                                    + kb * 64 + (l >> 4) * 16);
      acc[mi] = __builtin_amdgcn_mfma_f32_16x16x32_bf16(afr, bfr, acc[mi], 0, 0, 0);
    }
  }
  int r0 = (l >> 4) * 4, cq = l & 15;
#pragma unroll
  for (int mi = 0; mi < 4; ++mi)
#pragma unroll
    for (int reg = 0; reg < 4; ++reg) {
      int row = mi * 16 + r0 + reg, col = n0 + cq;
      gbuf[(size_t)row * ZDIM + col] = acc[mi][reg] + bias[col];
    }
}

// ------------------------------------------------- phase-1 GEMM: zpre = Xb @ Wx^T + gbuf
__global__ __launch_bounds__(256, 2) void k_gemm_p1(const unsigned short* __restrict__ Xb,
                                                    const unsigned short* __restrict__ Wt,
                                                    const float* __restrict__ gbuf,
                                                    unsigned short* __restrict__ zpre) {
  __shared__ unsigned char sm[32768];
  int tm = blockIdx.x, tn = blockIdx.y;
  int tid = threadIdx.x, l = tid & 63, w = tid >> 6;
  int m0w = (w & 1) * 64, n0w = (w >> 1) * 64;
  f32x4 acc[4][4] = {};

  for (int k0 = 0; k0 < HDIM; k0 += 64) {
#pragma unroll
    for (int j = 0; j < 8; ++j) {
      int c = j * 4 + w;
      int lane_row = l >> 3;
      int kb = (l & 7) * 16;
      const char* gsrc;
      if (c < 16) {
        int row = c * 8 + lane_row;
        gsrc = (const char*)Xb + (size_t)(tm * 128 + row) * 1024 + k0 * 2 + kb;
      } else {
        int row = (c - 16) * 8 + lane_row;
        gsrc = (const char*)Wt + (size_t)(tn * 128 + row) * 3072 + k0 * 2 + kb;
      }
      gl_lds16(gsrc, (char*)sm + c * 1024);
    }
    __syncthreads();

#pragma unroll
    for (int kk = 0; kk < 64; kk += 32) {
      short8 af[4], bf[4];
#pragma unroll
      for (int mi = 0; mi < 4; ++mi)
        af[mi] = *(const short8*)((const char*)sm + (size_t)(m0w + mi * 16 + (l & 15)) * 128
                                  + (kk + (l >> 4) * 8) * 2);
#pragma unroll
      for (int ni = 0; ni < 4; ++ni)
        bf[ni] = *(const short8*)((const char*)sm + 16384 + (size_t)(n0w + ni * 16 + (l & 15)) * 128
                                  + (kk + (l >> 4) * 8) * 2);
#pragma unroll
      for (int mi = 0; mi < 4; ++mi)
#pragma unroll
        for (int ni = 0; ni < 4; ++ni)
          acc[mi][ni] = __builtin_amdgcn_mfma_f32_16x16x32_bf16(af[mi], bf[ni], acc[mi][ni], 0, 0, 0);
    }
    __syncthreads();
  }

  int r0 = (l >> 4) * 4, cq = l & 15;
#pragma unroll
  for (int mi = 0; mi < 4; ++mi)
#pragma unroll
    for (int ni = 0; ni < 4; ++ni) {
      int col = tn * 128 + n0w + ni * 16 + cq;
#pragma unroll
      for (int reg = 0; reg < 4; ++reg) {
        int row = tm * 128 + m0w + mi * 16 + r0 + reg;
        float v = acc[mi][ni][reg] + gbuf[(size_t)(row & 63) * ZDIM + col];
        zpre[(size_t)row * ZDIM + col] = f2bf(v);
      }
    }
}

// ---------------------------------------------------------- persistent recurrence
// 128 wgs: dir(2) x colgroup(16 -> 32 h-cols) x batchgroup(4 -> 16 rows). 4 waves = 4 gates.
#define WGD 64   // wgs per direction

// Relaxed-poll grid barrier (per direction). One acquire fence per wg per step.
static __device__ __forceinline__ void gbar(unsigned* cnt, unsigned* epoch, unsigned e) {
  __syncthreads();
  if (threadIdx.x == 0) {
    unsigned old = __hip_atomic_fetch_add(cnt, 1u, __ATOMIC_RELEASE, __HIP_MEMORY_SCOPE_AGENT);
    if (old == WGD - 1u) {
      __hip_atomic_store(cnt, 0u, __ATOMIC_RELAXED, __HIP_MEMORY_SCOPE_AGENT);
      __hip_atomic_store(epoch, e, __ATOMIC_RELEASE, __HIP_MEMORY_SCOPE_AGENT);
    } else {
      long guard = 0;
      while (__hip_atomic_load(epoch, __ATOMIC_RELAXED, __HIP_MEMORY_SCOPE_AGENT) < e) {
        __builtin_amdgcn_s_sleep(1);
        if (++guard > (1L << 22)) break;   // hang guard
      }
    }
    __builtin_amdgcn_fence(__ATOMIC_ACQUIRE, "agent");
  }
  __syncthreads();
}

__global__ __launch_bounds__(256, 1) void k_rec(const unsigned short* __restrict__ Wt,
                                                const unsigned short* __restrict__ zpre,
                                                unsigned short* __restrict__ hbuf, // [2][2][64][512] bf16
                                                unsigned* __restrict__ sync_ws,
                                                float* __restrict__ out,
                                                float* __restrict__ hstate,
                                                float* __restrict__ cstate) {
  __shared__ short lwh[4 * 32 * 512];   // 128KB: [gate][col(32)][k(512)] bf16, XOR-swizzled
  __shared__ float zbuf[4][16][32];     // 8KB

  const int tid = threadIdx.x, l = tid & 63, gi = tid >> 6;   // wave = gate (i,f,o,u)
  const int wg = blockIdx.x;
  const int dir = wg >> 6, rr = wg & 63, cg = rr >> 2, bg = rr & 3;
  const int m0 = bg * 16, hc0 = cg * 32;

  unsigned* cnt   = sync_ws + dir * 64;        // 256B apart
  unsigned* epoch = sync_ws + dir * 64 + 32;   // 128B from cnt

  // stage Wh slice (gate gi, cols hc0..hc0+31) into LDS, resident all 256 steps.
  // content for (col,k): byte col*1024 + (k*2 ^ ((col&7)<<4))
#pragma unroll
  for (int col = 0; col < 32; ++col) {
    int kbs = l * 16;
    int kbyte = kbs ^ ((col & 7) << 4);
    short8 v = *(const short8*)((const char*)Wt
                + (size_t)(gi * 512 + hc0 + col) * 3072 + 1024 + kbyte);
    *(short8*)((char*)lwh + gi * 32768 + col * 1024 + kbs) = v;
  }

  const int r = tid >> 4, q = tid & 15;
  // zero-init h read-buffer 0 for our rows/cols
  {
    size_t hb = ((size_t)(0 * 2 + dir) * 64 + m0 + r) * 512 + hc0 + q;
    hbuf[hb] = 0;
    hbuf[hb + 16] = 0;
  }
  unsigned bar = 0;
  gbar(cnt, epoch, ++bar);

  float c0 = 0.f, c1 = 0.f, h0 = 0.f, h1 = 0.f;

  // prefetch zpre for first step into registers
  int t = dir ? (SEQL - 1) : 0;
  unsigned short zp[8];
  {
    size_t zo = ((size_t)t * 64 + m0 + r) * ZDIM + hc0 + q;
#pragma unroll
    for (int gg = 0; gg < 4; ++gg) {
      zp[gg]     = zpre[zo + gg * 512];
      zp[4 + gg] = zpre[zo + gg * 512 + 16];
    }
  }

  for (int s = 0; s < SEQL; ++s) {
    int rb = s & 1, wb = rb ^ 1;
    const char* hbase = (const char*)hbuf + (size_t)(rb * 2 + dir) * 65536;

    // z-tile: wave gi computes 16 rows x 32 cols of gate gi, K=512
    f32x4 acc0 = {0.f, 0.f, 0.f, 0.f}, acc1 = {0.f, 0.f, 0.f, 0.f};
#pragma unroll
    for (int kb = 0; kb < 16; ++kb) {
      short8 a = *(const short8*)(hbase + (size_t)(m0 + (l & 15)) * 1024
                                  + kb * 64 + (l >> 4) * 16);
      int kfrag = kb * 64 + (l >> 4) * 16;
      int kbyte = kfrag ^ ((l & 7) << 4);   // (col&7) == l&7 for both ni
      short8 b0 = *(const short8*)((const char*)lwh + gi * 32768 + (size_t)(l & 15) * 1024 + kbyte);
      short8 b1 = *(const short8*)((const char*)lwh + gi * 32768 + (size_t)(16 + (l & 15)) * 1024 + kbyte);
      acc0 = __builtin_amdgcn_mfma_f32_16x16x32_bf16(a, b0, acc0, 0, 0, 0);
      acc1 = __builtin_amdgcn_mfma_f32_16x16x32_bf16(a, b1, acc1, 0, 0, 0);
    }
    {
      int col = l & 15, row0 = (l >> 4) * 4;
#pragma unroll
      for (int reg = 0; reg < 4; ++reg) {
        zbuf[gi][row0 + reg][col]      = acc0[reg];
        zbuf[gi][row0 + reg][col + 16] = acc1[reg];
      }
    }
    __syncthreads();

    // gate math: thread (r,q) owns (row m0+r, cols hc0+q, hc0+q+16)
    float zi0 = zbuf[0][r][q]      + bf2f(zp[0]);
    float zf0 = zbuf[1][r][q]      + bf2f(zp[1]);
    float zo0 = zbuf[2][r][q]      + bf2f(zp[2]);
    float zu0 = zbuf[3][r][q]      + bf2f(zp[3]);
    float zi1 = zbuf[0][r][q + 16] + bf2f(zp[4]);
    float zf1 = zbuf[1][r][q + 16] + bf2f(zp[5]);
    float zo1 = zbuf[2][r][q + 16] + bf2f(zp[6]);
    float zu1 = zbuf[3][r][q + 16] + bf2f(zp[7]);

    c0 = sigm(zf0) * c0 + sigm(zi0) * tanh_f(zu0);
    h0 = sigm(zo0) * tanh_f(c0);
    c1 = sigm(zf1) * c1 + sigm(zi1) * tanh_f(zu1);
    h1 = sigm(zo1) * tanh_f(c1);

    size_t ob = ((size_t)(m0 + r) * SEQL + t) * 1024 + dir * 512 + hc0 + q;
    out[ob]      = h0;
    out[ob + 16] = h1;
    size_t hb = ((size_t)(wb * 2 + dir) * 64 + m0 + r) * 512 + hc0 + q;
    hbuf[hb]      = f2bf(h0);
    hbuf[hb + 16] = f2bf(h1);

    // prefetch next step's zpre BEFORE the barrier (hides L3 latency)
    if (s + 1 < SEQL) {
      t = dir ? (SEQL - 2 - s) : (s + 1);
      size_t zo = ((size_t)t * 64 + m0 + r) * ZDIM + hc0 + q;
#pragma unroll
      for (int gg = 0; gg < 4; ++gg) {
        zp[gg]     = zpre[zo + gg * 512];
        zp[4 + gg] = zpre[zo + gg * 512 + 16];
      }
    }

    gbar(cnt, epoch, ++bar);
  }

  size_t st = (size_t)(m0 + r) * 1024 + dir * 512 + hc0 + q;
  hstate[st]      = h0;
  hstate[st + 16] = h1;
  cstate[st]      = c0;
  cstate[st + 16] = c1;
}

// ---------------------------------------------------------------------- launch

extern "C" void kernel_launch(void* const* d_in, const int* in_sizes, int n_in,
                              void* d_out, int out_size, void* d_ws, size_t ws_size,
                              hipStream_t stream) {
  const float* x    = (const float*)d_in[0];
  const float* g    = (const float*)d_in[1];
  const float* W    = (const float*)d_in[2];
  const float* bias = (const float*)d_in[3];
  float* out = (float*)d_out;
  float* hstate = out + (size_t)16777216;            // 64*256*1024
  float* cstate = out + (size_t)16842752;            // + 64*1024

  char* ws = (char*)d_ws;
  unsigned*       sync_ws = (unsigned*)(ws + 0);              // 512B: cnt/epoch x2 dirs
  unsigned short* hbuf = (unsigned short*)(ws + 1024);        // 256KB
  unsigned short* Xb   = (unsigned short*)(ws + 263168);      // 16MB
  unsigned short* Wt   = (unsigned short*)(ws + 17040384);    // 6MB
  unsigned short* gbf  = (unsigned short*)(ws + 23331840);    // 64KB
  float*          gbuf = (float*)(ws + 23397376);             // 512KB
  unsigned short* zpre = (unsigned short*)(ws + 23921664);    // 64MB

  hipMemsetAsync((void*)sync_ws, 0, 512, stream);

  k_convx<<<4096, 256, 0, stream>>>(x, Xb);
  k_convg<<<16, 256, 0, stream>>>(g, gbf);
  k_trans<<<dim3(64, 48), 256, 0, stream>>>(W, Wt);
  k_gb<<<32, 256, 0, stream>>>(gbf, Wt, bias, gbuf);
  k_gemm_p1<<<dim3(128, 16), 256, 0, stream>>>(Xb, Wt, gbuf, zpre);
  k_rec<<<128, 256, 0, stream>>>(Wt, zpre, hbuf, sync_ws, out, hstate, cstate);
}